// Round 1
// baseline (268.353 us; speedup 1.0000x reference)
//
#include <hip/hip_runtime.h>
#include <stdint.h>

typedef uint32_t u32;
typedef uint64_t u64;

// BinaryNet on MI355X: everything after binarize() is {-1,0,+1}.
// Layer1 (9 taps, odd) -> exact +-1 per output -> 1 bit.
// Layer2 (36 taps, even) -> ternary -> (value bit, nonzero bit).
// All convs/FCs computed as XOR + popcount on packed sign bits.
//
// ws layout (u32 index):
//   [0..3]   w1p[c]    : 9-bit, bit 3*ky+kx
//   [8..23]  w2q[d]    : u64, 36-bit, bit 12*ky+4*kx+c
//   [24..55] w3lo[e]   : u64, bits 0..63 of 72-bit, bit 8*(3*ky+kx)+d
//   [56..71] w3hi[e]   : u32, bits 64..71
//   [72..79] wf1[j]    : 16-bit, bit e
//   [80]     wf2       : 8-bit, bit j

__global__ void prep_weights(const float* __restrict__ w1, const float* __restrict__ w2,
                             const float* __restrict__ w3, const float* __restrict__ wfc1,
                             const float* __restrict__ wfc2, u32* __restrict__ ws) {
  int t = threadIdx.x;
  u64* w2q  = (u64*)(ws + 8);
  u64* w3lo = (u64*)(ws + 24);
  u32* w3hi = ws + 56;
  u32* wf1  = ws + 72;
  if (t < 4) {
    u32 m = 0;
    for (int k = 0; k < 9; ++k) if (w1[t * 9 + k] < 0.f) m |= 1u << k;
    ws[t] = m;
  } else if (t >= 8 && t < 16) {
    int d = t - 8; u64 m = 0;
    for (int ky = 0; ky < 3; ++ky)
      for (int kx = 0; kx < 3; ++kx)
        for (int c = 0; c < 4; ++c)
          if (w2[d * 36 + c * 9 + ky * 3 + kx] < 0.f) m |= 1ull << (12 * ky + 4 * kx + c);
    w2q[d] = m;
  } else if (t >= 16 && t < 32) {
    int e = t - 16; u64 lo = 0; u32 hi = 0;
    for (int ky = 0; ky < 3; ++ky)
      for (int kx = 0; kx < 3; ++kx)
        for (int d = 0; d < 8; ++d)
          if (w3[e * 72 + d * 9 + ky * 3 + kx] < 0.f) {
            int bp = 8 * (3 * ky + kx) + d;
            if (bp < 64) lo |= 1ull << bp; else hi |= 1u << (bp - 64);
          }
    w3lo[e] = lo; w3hi[e] = hi;
  } else if (t >= 32 && t < 40) {
    int j = t - 32; u32 m = 0;
    for (int e = 0; e < 16; ++e) if (wfc1[j * 16 + e] < 0.f) m |= 1u << e;
    wf1[j] = m;
  } else if (t == 40) {
    u32 m = 0;
    for (int j = 0; j < 8; ++j) if (wfc2[j] < 0.f) m |= 1u << j;
    ws[80] = m;
  }
}

__global__ __launch_bounds__(256) void binnet(const float* __restrict__ x,
                                              const u32* __restrict__ ws,
                                              float* __restrict__ out) {
  __shared__ u64 stage[4][228];
  const int tid = threadIdx.x;
  const int wv = tid >> 6, lane = tid & 63;
  const int eb = blockIdx.x * 256 + wv * 64;  // first element of this wave's 64
  const float* xp = x + (size_t)eb * 225;
  u64* st = stage[wv];

  // ---- Stage: coalesced dword loads, ballot-pack sign bits into LDS ----
  #pragma unroll 9
  for (int t = 0; t < 225; ++t) {
    float v = xp[t * 64 + lane];
    u64 m = __ballot(v < 0.f);
    if (lane == 0) st[t] = m;
  }
  __syncthreads();

  // ---- Gather this element's 225 bits into 4 registers ----
  const int f0 = 225 * lane;
  const int w0 = f0 >> 6;
  const int sh = f0 & 63;
  u64 Wd[5];
  #pragma unroll
  for (int i = 0; i < 5; ++i) Wd[i] = st[w0 + i];
  u64 Bv[4];
  #pragma unroll
  for (int i = 0; i < 4; ++i)
    Bv[i] = (Wd[i] >> sh) | ((Wd[i + 1] << (63 - sh)) << 1);  // sh==0 -> 0 contribution

  // rows: rb[r] bit k = sign(x[b,0,r,k])
  u32 rb[15];
  #pragma unroll
  for (int r = 0; r < 15; ++r) {
    const int f = 15 * r, w = f >> 6, o = f & 63;
    u64 v = Bv[w] >> o;
    if (o > 49) v |= Bv[w + 1] << (64 - o);
    rb[r] = (u32)v & 0x7FFFu;
  }

  // ---- Layer 1: 4ch, 15x15 -> 7x7, 9 taps (always +-1 out) ----
  const u32 w1p0 = ws[0], w1p1 = ws[1], w1p2 = ws[2], w1p3 = ws[3];
  u64 a1[4] = {0, 0, 0, 0};  // bit 4*(7*oy+ox)+c, 1 = negative
  int pix = 0;
  #pragma unroll
  for (int oy = 0; oy < 7; ++oy) {
    const u32 r0 = rb[2 * oy], r1 = rb[2 * oy + 1], r2 = rb[2 * oy + 2];
    #pragma unroll
    for (int ox = 0; ox < 7; ++ox) {
      const u32 t9 = ((r0 >> (2 * ox)) & 7) | (((r1 >> (2 * ox)) & 7) << 3)
                   | (((r2 >> (2 * ox)) & 7) << 6);
      u32 nib = 0;
      nib |= (u32)(__popc(t9 ^ w1p0) >= 5) << 0;
      nib |= (u32)(__popc(t9 ^ w1p1) >= 5) << 1;
      nib |= (u32)(__popc(t9 ^ w1p2) >= 5) << 2;
      nib |= (u32)(__popc(t9 ^ w1p3) >= 5) << 3;
      a1[pix >> 4] |= (u64)nib << ((pix & 15) * 4);
      ++pix;
    }
  }

  // ---- Layer 2: 8ch, 7x7 -> 3x3, 36 taps (ternary out) ----
  const u64* w2qp = (const u64*)(ws + 8);
  u64 W2[8];
  #pragma unroll
  for (int d = 0; d < 8; ++d) W2[d] = w2qp[d];
  u64 v2lo = 0, nz2lo = 0; u32 v2hi = 0, nz2hi = 0;  // bit 8*(3*oy+ox)+d
  #pragma unroll
  for (int oy = 0; oy < 3; ++oy) {
    #pragma unroll
    for (int ox = 0; ox < 3; ++ox) {
      u64 T = 0;
      #pragma unroll
      for (int ky = 0; ky < 3; ++ky) {
        const int p = 4 * (7 * (2 * oy + ky) + 2 * ox);
        const int w = p >> 6, o = p & 63;
        u64 v = a1[w] >> o;
        if (o > 52) v |= a1[w + 1] << (64 - o);
        T |= (v & 0xFFFull) << (12 * ky);
      }
      const int pix2 = 3 * oy + ox;
      u32 bv = 0, bz = 0;
      #pragma unroll
      for (int d = 0; d < 8; ++d) {
        const int cnt = __popcll(T ^ W2[d]);  // #neg products of 36
        bv |= (u32)(cnt > 18) << d;           // sum = 36-2cnt < 0
        bz |= (u32)(cnt != 18) << d;          // nonzero
      }
      if (pix2 < 8) { v2lo |= (u64)bv << (8 * pix2); nz2lo |= (u64)bz << (8 * pix2); }
      else          { v2hi = bv; nz2hi = bz; }
    }
  }

  // ---- Layer 3: 16ch, 3x3 -> 1x1, 72 taps, ternary in/out ----
  const u64* w3lo = (const u64*)(ws + 24);
  const u32* w3hi = ws + 56;
  u64 W3L[16]; u32 W3H[16];
  #pragma unroll
  for (int e = 0; e < 16; ++e) { W3L[e] = w3lo[e]; W3H[e] = w3hi[e]; }
  const int nztot = __popcll(nz2lo) + __popc(nz2hi);
  u32 s3v = 0, s3nz = 0;
  #pragma unroll
  for (int e = 0; e < 16; ++e) {
    const int cnt = __popcll(nz2lo & (v2lo ^ W3L[e])) + __popc(nz2hi & (v2hi ^ W3H[e]));
    const int s = nztot - 2 * cnt;
    s3v  |= (u32)(s < 0) << e;
    s3nz |= (u32)(s != 0) << e;
  }

  // ---- FC1: 16 -> 8, ternary ----
  const u32* wf1 = ws + 72;
  u32 WF1[8];
  #pragma unroll
  for (int j = 0; j < 8; ++j) WF1[j] = wf1[j];
  const int n3 = __popc(s3nz);
  u32 hv = 0, hz = 0;
  #pragma unroll
  for (int j = 0; j < 8; ++j) {
    const int c2 = __popc(s3nz & (s3v ^ WF1[j]));
    const int s = n3 - 2 * c2;
    hv |= (u32)(s < 0) << j;
    hz |= (u32)(s != 0) << j;
  }

  // ---- FC2: 8 -> 1 (no hardtanh) ----
  const u32 wf2 = ws[80];
  const int c3 = __popc(hz & (hv ^ wf2));
  const int sfin = __popc(hz) - 2 * c3;
  out[eb + lane] = (float)sfin;
}

extern "C" void kernel_launch(void* const* d_in, const int* in_sizes, int n_in,
                              void* d_out, int out_size, void* d_ws, size_t ws_size,
                              hipStream_t stream) {
  const float* x    = (const float*)d_in[0];
  const float* w1   = (const float*)d_in[1];
  const float* w2   = (const float*)d_in[2];
  const float* w3   = (const float*)d_in[3];
  const float* wfc1 = (const float*)d_in[4];
  const float* wfc2 = (const float*)d_in[5];
  u32* ws = (u32*)d_ws;
  float* out = (float*)d_out;
  const int B = in_sizes[0] / 225;  // 131072

  prep_weights<<<1, 64, 0, stream>>>(w1, w2, w3, wfc1, wfc2, ws);
  binnet<<<B / 256, 256, 0, stream>>>(x, ws, out);
}

// Round 3
// 191.593 us; speedup vs baseline: 1.4006x; 1.4006x over previous
//
#include <hip/hip_runtime.h>
#include <stdint.h>

typedef uint32_t u32;
typedef uint64_t u64;

// BinaryNet on MI355X: everything after binarize() is {-1,0,+1}.
// Layer1 (9 taps, odd) -> exact +-1 per output -> 1 bit.
// Layer2 (36 taps, even) -> ternary -> (value bit, nonzero bit).
// All convs/FCs computed as XOR + popcount on packed sign bits.
//
// ws layout (u32 index) — total footprint 324 bytes (ws[0..80]), matching the
// R1-proven bound. R2's 512-byte zeroing is the prime suspect for the context
// fault (out showed values no kernel here can produce; outputs are bounded
// by construction, so only a fault explains absmax ~2^32).
//   [0..3]   w1p[c]    : 9-bit, bit 3*ky+kx
//   [8..23]  w2q[d]    : u64, 36-bit, bit 12*ky+4*kx+c
//   [24..55] w3lo[e]   : u64, bits 0..63 of 72-bit, bit 8*(3*ky+kx)+d
//   [56..71] w3hi[e]   : u32, bits 64..71
//   [72..79] wf1[j]    : 16-bit, bit e
//   [80]     wf2       : 8-bit, bit j

// ---------------- weight prep: <=7 independent loads/thread, atomicOr ----------------
__global__ void prep_weights(const float* __restrict__ w1, const float* __restrict__ w2,
                             const float* __restrict__ w3, const float* __restrict__ wfc1,
                             const float* __restrict__ wfc2, u32* __restrict__ ws) {
  const int tid = threadIdx.x;
  if (tid < 81) ws[tid] = 0;   // exactly the R1-proven 324-byte footprint
  __syncthreads();
  for (int i = tid; i < 1612; i += 256) {
    if (i < 36) {                       // w1 [4][9]
      const int c = i / 9, k = i % 9;
      if (w1[i] < 0.f) atomicOr(&ws[c], 1u << k);
    } else if (i < 324) {               // w2 [8][4][3][3]
      const int j = i - 36, d = j / 36, r = j % 36;
      const int c = r / 9, t = r % 9, ky = t / 3, kx = t % 3;
      const int bp = 12 * ky + 4 * kx + c;
      if (w2[j] < 0.f) atomicOr(&ws[8 + 2 * d + (bp >> 5)], 1u << (bp & 31));
    } else if (i < 1476) {              // w3 [16][8][3][3]
      const int j = i - 324, e = j / 72, r = j % 72;
      const int d = r / 9, t = r % 9, ky = t / 3, kx = t % 3;
      const int bp = 8 * (3 * ky + kx) + d;
      if (w3[j] < 0.f) {
        if (bp < 64) atomicOr(&ws[24 + 2 * e + (bp >> 5)], 1u << (bp & 31));
        else         atomicOr(&ws[56 + e], 1u << (bp - 64));
      }
    } else if (i < 1604) {              // wfc1 [8][16]
      const int j = i - 1476, row = j / 16, e = j % 16;
      if (wfc1[j] < 0.f) atomicOr(&ws[72 + row], 1u << e);
    } else {                            // wfc2 [1][8]
      const int j = i - 1604;
      if (wfc2[j] < 0.f) atomicOr(&ws[80], 1u << j);
    }
  }
}

// ---------------- fused kernel: float4 sign-pack staging + R1-verified eval ----------------
__global__ __launch_bounds__(256) void binnet(const float4* __restrict__ x4,
                                              const u32* __restrict__ ws,
                                              float* __restrict__ out) {
  __shared__ u64 st[4][228];
  const int tid = threadIdx.x;
  const int b = blockIdx.x;

  // ---- Stage: thread builds whole u64 words solo (no ballot, no cross-lane).
  // Word (g,t) = signs of flat floats [ (256b+64g)*225 + 64t .. +63 ].
  // 16 independent float4 loads per word -> deep MLP, latency fully hidden.
  #pragma unroll
  for (int r = 0; r < 4; ++r) {
    const int W = tid + r * 256;        // 900 words per block
    if (W < 900) {
      const int g = W / 225, t = W - 225 * g;
      const float4* p = x4 + (size_t)b * 14400 + g * 3600 + t * 16;
      u64 w = 0;
      #pragma unroll
      for (int k = 0; k < 16; ++k) {
        const float4 f = p[k];
        const u32 n = (__float_as_uint(f.x) >> 31)
                    | ((__float_as_uint(f.y) >> 31) << 1)
                    | ((__float_as_uint(f.z) >> 31) << 2)
                    | ((__float_as_uint(f.w) >> 31) << 3);
        w |= (u64)n << (4 * k);
      }
      st[g][t] = w;
    }
  }
  if (tid < 12) st[tid & 3][225 + (tid >> 2)] = 0;  // zero tail words (insurance)
  __syncthreads();

  // ---- Eval: byte-identical to the R1-passing kernel ----
  const int wv = tid >> 6, lane = tid & 63;
  const u64* stw = st[wv];
  const int f0 = 225 * lane;
  const int w0 = f0 >> 6;
  const int sh = f0 & 63;
  u64 Wd[5];
  #pragma unroll
  for (int i = 0; i < 5; ++i) Wd[i] = stw[w0 + i];
  u64 Bv[4];
  #pragma unroll
  for (int i = 0; i < 4; ++i)
    Bv[i] = (Wd[i] >> sh) | ((Wd[i + 1] << (63 - sh)) << 1);  // sh==0 -> 0 contribution

  // rows: rb[r] bit k = sign(x[b,0,r,k])
  u32 rb[15];
  #pragma unroll
  for (int r = 0; r < 15; ++r) {
    const int f = 15 * r, w = f >> 6, o = f & 63;
    u64 v = Bv[w] >> o;
    if (o > 49) v |= Bv[w + 1] << (64 - o);
    rb[r] = (u32)v & 0x7FFFu;
  }

  // ---- Layer 1: 4ch, 15x15 -> 7x7, 9 taps (always +-1 out) ----
  const u32 w1p0 = ws[0], w1p1 = ws[1], w1p2 = ws[2], w1p3 = ws[3];
  u64 a1[4] = {0, 0, 0, 0};  // bit 4*(7*oy+ox)+c, 1 = negative
  int pix = 0;
  #pragma unroll
  for (int oy = 0; oy < 7; ++oy) {
    const u32 r0 = rb[2 * oy], r1 = rb[2 * oy + 1], r2 = rb[2 * oy + 2];
    #pragma unroll
    for (int ox = 0; ox < 7; ++ox) {
      const u32 t9 = ((r0 >> (2 * ox)) & 7) | (((r1 >> (2 * ox)) & 7) << 3)
                   | (((r2 >> (2 * ox)) & 7) << 6);
      u32 nib = 0;
      nib |= (u32)(__popc(t9 ^ w1p0) >= 5) << 0;
      nib |= (u32)(__popc(t9 ^ w1p1) >= 5) << 1;
      nib |= (u32)(__popc(t9 ^ w1p2) >= 5) << 2;
      nib |= (u32)(__popc(t9 ^ w1p3) >= 5) << 3;
      a1[pix >> 4] |= (u64)nib << ((pix & 15) * 4);
      ++pix;
    }
  }

  // ---- Layer 2: 8ch, 7x7 -> 3x3, 36 taps (ternary out) ----
  const u64* w2qp = (const u64*)(ws + 8);
  u64 W2[8];
  #pragma unroll
  for (int d = 0; d < 8; ++d) W2[d] = w2qp[d];
  u64 v2lo = 0, nz2lo = 0; u32 v2hi = 0, nz2hi = 0;  // bit 8*(3*oy+ox)+d
  #pragma unroll
  for (int oy = 0; oy < 3; ++oy) {
    #pragma unroll
    for (int ox = 0; ox < 3; ++ox) {
      u64 T = 0;
      #pragma unroll
      for (int ky = 0; ky < 3; ++ky) {
        const int p = 4 * (7 * (2 * oy + ky) + 2 * ox);
        const int w = p >> 6, o = p & 63;
        u64 v = a1[w] >> o;
        if (o > 52) v |= a1[w + 1] << (64 - o);
        T |= (v & 0xFFFull) << (12 * ky);
      }
      const int pix2 = 3 * oy + ox;
      u32 bv = 0, bz = 0;
      #pragma unroll
      for (int d = 0; d < 8; ++d) {
        const int cnt = __popcll(T ^ W2[d]);  // #neg products of 36
        bv |= (u32)(cnt > 18) << d;           // sum = 36-2cnt < 0
        bz |= (u32)(cnt != 18) << d;          // nonzero
      }
      if (pix2 < 8) { v2lo |= (u64)bv << (8 * pix2); nz2lo |= (u64)bz << (8 * pix2); }
      else          { v2hi = bv; nz2hi = bz; }
    }
  }

  // ---- Layer 3: 16ch, 3x3 -> 1x1, 72 taps, ternary in/out ----
  const u64* w3lo = (const u64*)(ws + 24);
  const u32* w3hi = ws + 56;
  u64 W3L[16]; u32 W3H[16];
  #pragma unroll
  for (int e = 0; e < 16; ++e) { W3L[e] = w3lo[e]; W3H[e] = w3hi[e]; }
  const int nztot = __popcll(nz2lo) + __popc(nz2hi);
  u32 s3v = 0, s3nz = 0;
  #pragma unroll
  for (int e = 0; e < 16; ++e) {
    const int cnt = __popcll(nz2lo & (v2lo ^ W3L[e])) + __popc(nz2hi & (v2hi ^ W3H[e]));
    const int s = nztot - 2 * cnt;
    s3v  |= (u32)(s < 0) << e;
    s3nz |= (u32)(s != 0) << e;
  }

  // ---- FC1: 16 -> 8, ternary ----
  const u32* wf1 = ws + 72;
  u32 WF1[8];
  #pragma unroll
  for (int j = 0; j < 8; ++j) WF1[j] = wf1[j];
  const int n3 = __popc(s3nz);
  u32 hv = 0, hz = 0;
  #pragma unroll
  for (int j = 0; j < 8; ++j) {
    const int c2 = __popc(s3nz & (s3v ^ WF1[j]));
    const int s = n3 - 2 * c2;
    hv |= (u32)(s < 0) << j;
    hz |= (u32)(s != 0) << j;
  }

  // ---- FC2: 8 -> 1 (no hardtanh) ----
  const u32 wf2 = ws[80];
  const int c3 = __popc(hz & (hv ^ wf2));
  const int sfin = __popc(hz) - 2 * c3;
  out[b * 256 + wv * 64 + lane] = (float)sfin;
}

extern "C" void kernel_launch(void* const* d_in, const int* in_sizes, int n_in,
                              void* d_out, int out_size, void* d_ws, size_t ws_size,
                              hipStream_t stream) {
  const float* x    = (const float*)d_in[0];
  const float* w1   = (const float*)d_in[1];
  const float* w2   = (const float*)d_in[2];
  const float* w3   = (const float*)d_in[3];
  const float* wfc1 = (const float*)d_in[4];
  const float* wfc2 = (const float*)d_in[5];
  u32* ws = (u32*)d_ws;
  float* out = (float*)d_out;
  const int B = in_sizes[0] / 225;  // 131072

  prep_weights<<<1, 256, 0, stream>>>(w1, w2, w3, wfc1, wfc2, ws);
  binnet<<<B / 256, 256, 0, stream>>>((const float4*)x, ws, out);
}